// Round 1
// baseline (618.332 us; speedup 1.0000x reference)
//
#include <hip/hip_runtime.h>
#include <math.h>

// Problem constants (match reference)
#define S 64
#define NC 64          // channels
#define HF 128
#define WF 128
#define HW (HF * WF)   // 16384, channel stride in feat
#define SS (S * S)     // 4096, channel stride in out
#define EXPANDF 1.25f
#define FEAT_DOWN_INV 0.125f
#define DEG2RADF 0.017453292519943295f

__global__ __launch_bounds__(256) void RotatedROIPool_kernel(
    const float* __restrict__ feat,   // (B, C, HF, WF)
    const float* __restrict__ obb,    // (N, 5)
    const int*   __restrict__ bix,    // (N,)
    float*       __restrict__ out)    // (N, C, S, S)
{
    const int gid = blockIdx.x * 256 + threadIdx.x;   // N*S*S threads total
    const int n   = gid >> 12;          // / (S*S)
    const int rem = gid & (SS - 1);
    const int i   = rem >> 6;           // row
    const int j   = rem & (S - 1);      // col (lane-contiguous -> coalesced store)

    // --- per-ROI affine (redundant across the 4096 threads of an ROI, but cheap) ---
    const float o0 = obb[n * 5 + 0];
    const float o1 = obb[n * 5 + 1];
    const float o2 = obb[n * 5 + 2];
    const float o3 = obb[n * 5 + 3];
    const float o4 = obb[n * 5 + 4];

    const float cx = o0 * FEAT_DOWN_INV;
    const float cy = o1 * FEAT_DOWN_INV;
    const float ws = o2 * FEAT_DOWN_INV * EXPANDF;
    const float hs = o3 * FEAT_DOWN_INV * EXPANDF;
    const float th = o4 * DEG2RADF;

    float sth, cth;
    sincosf(th, &sth, &cth);

    const float sx  = ws * (1.0f / (float)S);
    const float sy  = hs * (1.0f / (float)S);
    const float m00 = cth * sx;
    const float m01 = -sth * sy;
    const float m02 = cx;
    const float m10 = EXPANDF * sx;     // replicate reference exactly
    const float m11 = cth * sy;
    const float m12 = cy;

    // normalized grid coords for this (i, j)
    const float xg = (2.0f * (float)j + 1.0f) * (1.0f / (float)S) - 1.0f;
    const float yg = (2.0f * (float)i + 1.0f) * (1.0f / (float)S) - 1.0f;

    const float gx = m00 * xg + m01 * yg + m02;
    const float gy = m10 * xg + m11 * yg + m12;

    // to image coords (align_corners=False)
    const float ix = ((gx + 1.0f) * (float)WF - 1.0f) * 0.5f;
    const float iy = ((gy + 1.0f) * (float)HF - 1.0f) * 0.5f;

    const float x0f = floorf(ix);
    const float y0f = floorf(iy);
    const float wx1 = ix - x0f;
    const float wy1 = iy - y0f;
    const float wx0 = 1.0f - wx1;
    const float wy0 = 1.0f - wy1;

    const int x0 = (int)x0f;
    const int y0 = (int)y0f;
    const int x1 = x0 + 1;
    const int y1 = y0 + 1;

    // validity folded into the weights (reference: clamp index, multiply by valid)
    const float vx0 = (x0 >= 0 && x0 < WF) ? 1.0f : 0.0f;
    const float vx1 = (x1 >= 0 && x1 < WF) ? 1.0f : 0.0f;
    const float vy0 = (y0 >= 0 && y0 < HF) ? 1.0f : 0.0f;
    const float vy1 = (y1 >= 0 && y1 < HF) ? 1.0f : 0.0f;

    const float w00 = wy0 * wx0 * vy0 * vx0;
    const float w01 = wy0 * wx1 * vy0 * vx1;
    const float w10 = wy1 * wx0 * vy1 * vx0;
    const float w11 = wy1 * wx1 * vy1 * vx1;

    const int x0c = min(max(x0, 0), WF - 1);
    const int x1c = min(max(x1, 0), WF - 1);
    const int y0c = min(max(y0, 0), HF - 1);
    const int y1c = min(max(y1, 0), HF - 1);

    const int o00 = y0c * WF + x0c;
    const int o01 = y0c * WF + x1c;
    const int o10 = y1c * WF + x0c;
    const int o11 = y1c * WF + x1c;

    const int b = bix[n];
    const float* __restrict__ p = feat + (size_t)b * NC * HW;
    float* __restrict__ op = out + (size_t)n * NC * SS + (size_t)i * S + (size_t)j;

#pragma unroll 4
    for (int c = 0; c < NC; ++c) {
        const float v = w00 * p[o00] + w01 * p[o01] + w10 * p[o10] + w11 * p[o11];
        *op = v;
        p  += HW;
        op += SS;
    }
}

extern "C" void kernel_launch(void* const* d_in, const int* in_sizes, int n_in,
                              void* d_out, int out_size, void* d_ws, size_t ws_size,
                              hipStream_t stream) {
    const float* feat = (const float*)d_in[0];
    const float* obb  = (const float*)d_in[1];
    const int*   bx   = (const int*)d_in[2];
    float* out = (float*)d_out;

    const int N = in_sizes[1] / 5;              // 256
    const int total = N * S * S;                // 1,048,576 threads
    const int blocks = total / 256;             // 4096

    RotatedROIPool_kernel<<<blocks, 256, 0, stream>>>(feat, obb, bx, out);
}

// Round 2
// 305.751 us; speedup vs baseline: 2.0223x; 2.0223x over previous
//
#include <hip/hip_runtime.h>
#include <math.h>

// Problem constants (match reference)
#define S 64
#define NC 64          // channels
#define CT 8           // channels per block (grid.y = NC/CT)
#define HF 128
#define WF 128
#define HW (HF * WF)   // 16384, channel stride in feat
#define SS (S * S)     // 4096, channel stride in out
#define EXPANDF 1.25f
#define FEAT_DOWN_INV 0.125f
#define DEG2RADF 0.017453292519943295f

__global__ __launch_bounds__(256) void RotatedROIPool_kernel(
    const float* __restrict__ feat,   // (B, C, HF, WF)
    const float* __restrict__ obb,    // (N, 5)
    const int*   __restrict__ bix,    // (N,)
    float*       __restrict__ out)    // (N, C, S, S)
{
    const int gid = blockIdx.x * 256 + threadIdx.x;   // N*S*S threads per c-tile
    const int n   = gid >> 12;          // / (S*S)
    const int rem = gid & (SS - 1);
    const int i   = rem >> 6;           // row
    const int j   = rem & (S - 1);      // col (lane-contiguous -> coalesced store)
    const int c0  = blockIdx.y * CT;    // channel tile (slow grid dim -> L2 phase-sync)

    // --- per-ROI affine (redundant across threads of an ROI, but cheap) ---
    const float o0 = obb[n * 5 + 0];
    const float o1 = obb[n * 5 + 1];
    const float o2 = obb[n * 5 + 2];
    const float o3 = obb[n * 5 + 3];
    const float o4 = obb[n * 5 + 4];

    const float cx = o0 * FEAT_DOWN_INV;
    const float cy = o1 * FEAT_DOWN_INV;
    const float ws = o2 * FEAT_DOWN_INV * EXPANDF;
    const float hs = o3 * FEAT_DOWN_INV * EXPANDF;
    const float th = o4 * DEG2RADF;

    float sth, cth;
    sincosf(th, &sth, &cth);

    const float sx  = ws * (1.0f / (float)S);
    const float sy  = hs * (1.0f / (float)S);
    const float m00 = cth * sx;
    const float m01 = -sth * sy;
    const float m02 = cx;
    const float m10 = EXPANDF * sx;     // replicate reference exactly
    const float m11 = cth * sy;
    const float m12 = cy;

    // normalized grid coords for this (i, j)
    const float xg = (2.0f * (float)j + 1.0f) * (1.0f / (float)S) - 1.0f;
    const float yg = (2.0f * (float)i + 1.0f) * (1.0f / (float)S) - 1.0f;

    const float gx = m00 * xg + m01 * yg + m02;
    const float gy = m10 * xg + m11 * yg + m12;

    // to image coords (align_corners=False)
    const float ix = ((gx + 1.0f) * (float)WF - 1.0f) * 0.5f;
    const float iy = ((gy + 1.0f) * (float)HF - 1.0f) * 0.5f;

    const float x0f = floorf(ix);
    const float y0f = floorf(iy);
    const float wx1 = ix - x0f;
    const float wy1 = iy - y0f;
    const float wx0 = 1.0f - wx1;
    const float wy0 = 1.0f - wy1;

    const int x0 = (int)x0f;
    const int y0 = (int)y0f;
    const int x1 = x0 + 1;
    const int y1 = y0 + 1;

    // validity folded into the weights (reference: clamp index, multiply by valid)
    const float vx0 = (x0 >= 0 && x0 < WF) ? 1.0f : 0.0f;
    const float vx1 = (x1 >= 0 && x1 < WF) ? 1.0f : 0.0f;
    const float vy0 = (y0 >= 0 && y0 < HF) ? 1.0f : 0.0f;
    const float vy1 = (y1 >= 0 && y1 < HF) ? 1.0f : 0.0f;

    const float w00 = wy0 * wx0 * vy0 * vx0;
    const float w01 = wy0 * wx1 * vy0 * vx1;
    const float w10 = wy1 * wx0 * vy1 * vx0;
    const float w11 = wy1 * wx1 * vy1 * vx1;

    const int x0c = min(max(x0, 0), WF - 1);
    const int x1c = min(max(x1, 0), WF - 1);
    const int y0c = min(max(y0, 0), HF - 1);
    const int y1c = min(max(y1, 0), HF - 1);

    const int o00 = y0c * WF + x0c;
    const int o01 = y0c * WF + x1c;
    const int o10 = y1c * WF + x0c;
    const int o11 = y1c * WF + x1c;

    const int b = bix[n];
    const float* __restrict__ p =
        feat + (size_t)b * NC * HW + (size_t)c0 * HW;

    // --- batch all 32 gathers first (MLP), then compute + store ---
    float v00[CT], v01[CT], v10[CT], v11[CT];
    {
        const float* pc = p;
#pragma unroll
        for (int c = 0; c < CT; ++c) {
            v00[c] = pc[o00];
            v01[c] = pc[o01];
            v10[c] = pc[o10];
            v11[c] = pc[o11];
            pc += HW;
        }
    }

    float* __restrict__ op =
        out + (size_t)n * NC * SS + (size_t)c0 * SS + (size_t)i * S + (size_t)j;
#pragma unroll
    for (int c = 0; c < CT; ++c) {
        *op = w00 * v00[c] + w01 * v01[c] + w10 * v10[c] + w11 * v11[c];
        op += SS;
    }
}

extern "C" void kernel_launch(void* const* d_in, const int* in_sizes, int n_in,
                              void* d_out, int out_size, void* d_ws, size_t ws_size,
                              hipStream_t stream) {
    const float* feat = (const float*)d_in[0];
    const float* obb  = (const float*)d_in[1];
    const int*   bx   = (const int*)d_in[2];
    float* out = (float*)d_out;

    const int N = in_sizes[1] / 5;              // 256
    const int spatial_blocks = N * S * S / 256; // 4096
    dim3 grid(spatial_blocks, NC / CT, 1);      // y = channel tile (slowest)

    RotatedROIPool_kernel<<<grid, 256, 0, stream>>>(feat, obb, bx, out);
}

// Round 3
// 251.937 us; speedup vs baseline: 2.4543x; 1.2136x over previous
//
#include <hip/hip_runtime.h>
#include <math.h>

// Problem constants (match reference)
#define S 64
#define NC 64          // channels
#define CT 8           // channels per block (grid.y = NC/CT)
#define HF 128
#define WF 128
#define HW (HF * WF)   // 16384, channel stride in feat
#define SS (S * S)     // 4096, channel stride in out
#define EXPANDF 1.25f
#define FEAT_DOWN_INV 0.125f
#define DEG2RADF 0.017453292519943295f

__global__ __launch_bounds__(256) void RotatedROIPool_kernel(
    const float* __restrict__ feat,   // (B, C, HF, WF)
    const float* __restrict__ obb,    // (N, 5)
    const int*   __restrict__ bix,    // (N,)
    float*       __restrict__ out)    // (N, C, S, S)
{
    const int tid   = threadIdx.x;
    const int pid   = blockIdx.x;            // N * 16 patches
    const int n     = pid >> 4;
    const int patch = pid & 15;              // 4x4 patches of 16x16 samples
    const int pi    = (patch >> 2) << 4;     // patch row origin
    const int pj    = (patch & 3)  << 4;     // patch col origin

    // wave = 8x8 sub-patch: compact image footprint per gather instruction
    const int w    = tid >> 6;               // wave id 0..3
    const int lane = tid & 63;
    const int i = pi + ((w >> 1) << 3) + (lane >> 3);   // sample row
    const int j = pj + ((w & 1)  << 3) + (lane & 7);    // sample col
    const int c0 = blockIdx.y * CT;          // channel tile (slow dim -> L2 phase sync)

    // --- per-ROI affine ---
    const float o0 = obb[n * 5 + 0];
    const float o1 = obb[n * 5 + 1];
    const float o2 = obb[n * 5 + 2];
    const float o3 = obb[n * 5 + 3];
    const float o4 = obb[n * 5 + 4];

    const float cx = o0 * FEAT_DOWN_INV;
    const float cy = o1 * FEAT_DOWN_INV;
    const float ws = o2 * FEAT_DOWN_INV * EXPANDF;
    const float hs = o3 * FEAT_DOWN_INV * EXPANDF;
    const float th = o4 * DEG2RADF;

    float sth, cth;
    sincosf(th, &sth, &cth);

    const float sx  = ws * (1.0f / (float)S);
    const float sy  = hs * (1.0f / (float)S);
    const float m00 = cth * sx;
    const float m01 = -sth * sy;
    const float m02 = cx;
    const float m10 = EXPANDF * sx;     // replicate reference exactly (diagonal quirk)
    const float m11 = cth * sy;
    const float m12 = cy;

    const float xg = (2.0f * (float)j + 1.0f) * (1.0f / (float)S) - 1.0f;
    const float yg = (2.0f * (float)i + 1.0f) * (1.0f / (float)S) - 1.0f;

    const float gx = m00 * xg + m01 * yg + m02;
    const float gy = m10 * xg + m11 * yg + m12;

    const float ix = ((gx + 1.0f) * (float)WF - 1.0f) * 0.5f;
    const float iy = ((gy + 1.0f) * (float)HF - 1.0f) * 0.5f;

    const float x0f = floorf(ix);
    const float y0f = floorf(iy);
    const float wx1 = ix - x0f;
    const float wy1 = iy - y0f;
    const float wx0 = 1.0f - wx1;
    const float wy0 = 1.0f - wy1;

    const int x0 = (int)x0f;
    const int y0 = (int)y0f;
    const int x1 = x0 + 1;
    const int y1 = y0 + 1;

    const float vx0 = (x0 >= 0 && x0 < WF) ? 1.0f : 0.0f;
    const float vx1 = (x1 >= 0 && x1 < WF) ? 1.0f : 0.0f;
    const float vy0 = (y0 >= 0 && y0 < HF) ? 1.0f : 0.0f;
    const float vy1 = (y1 >= 0 && y1 < HF) ? 1.0f : 0.0f;

    const float w00 = wy0 * wx0 * vy0 * vx0;
    const float w01 = wy0 * wx1 * vy0 * vx1;
    const float w10 = wy1 * wx0 * vy1 * vx0;
    const float w11 = wy1 * wx1 * vy1 * vx1;

    const int x0c = min(max(x0, 0), WF - 1);
    const int x1c = min(max(x1, 0), WF - 1);
    const int y0c = min(max(y0, 0), HF - 1);
    const int y1c = min(max(y1, 0), HF - 1);

    const int o00 = y0c * WF + x0c;
    const int o01 = y0c * WF + x1c;
    const int o10 = y1c * WF + x0c;
    const int o11 = y1c * WF + x1c;

    const int b = bix[n];
    const float* __restrict__ p =
        feat + (size_t)b * NC * HW + (size_t)c0 * HW;

    float* __restrict__ op =
        out + (size_t)n * NC * SS + (size_t)c0 * SS + (size_t)i * S + (size_t)j;

    // 2 groups of 4 channels: 16 gathers in flight (MLP), then compute + nt-store
#pragma unroll
    for (int g = 0; g < CT / 4; ++g) {
        float v00[4], v01[4], v10[4], v11[4];
        const float* pc = p + (size_t)g * 4 * HW;
#pragma unroll
        for (int c = 0; c < 4; ++c) {
            v00[c] = pc[o00];
            v01[c] = pc[o01];
            v10[c] = pc[o10];
            v11[c] = pc[o11];
            pc += HW;
        }
        float* oc = op + (size_t)g * 4 * SS;
#pragma unroll
        for (int c = 0; c < 4; ++c) {
            const float v = w00 * v00[c] + w01 * v01[c] + w10 * v10[c] + w11 * v11[c];
            __builtin_nontemporal_store(v, oc);   // write-once stream: keep out of L2
            oc += SS;
        }
    }
}

extern "C" void kernel_launch(void* const* d_in, const int* in_sizes, int n_in,
                              void* d_out, int out_size, void* d_ws, size_t ws_size,
                              hipStream_t stream) {
    const float* feat = (const float*)d_in[0];
    const float* obb  = (const float*)d_in[1];
    const int*   bx   = (const int*)d_in[2];
    float* out = (float*)d_out;

    const int N = in_sizes[1] / 5;              // 256
    dim3 grid(N * 16, NC / CT, 1);              // 16 patches of 16x16 per ROI

    RotatedROIPool_kernel<<<grid, 256, 0, stream>>>(feat, obb, bx, out);
}

// Round 4
// 174.745 us; speedup vs baseline: 3.5385x; 1.4417x over previous
//
#include <hip/hip_runtime.h>
#include <math.h>

// Problem constants (match reference)
#define S 64
#define NC 64          // channels
#define CT 16          // channels per block (grid.y = NC/CT); 16 ch = one 64B line in NHWC
#define HF 128
#define WF 128
#define HW (HF * WF)   // 16384
#define SS (S * S)     // 4096, channel stride in out
#define EXPANDF 1.25f
#define FEAT_DOWN_INV 0.125f
#define DEG2RADF 0.017453292519943295f

// ---- NCHW -> NHWC transpose (feat is only 8 MB; ~few us) ----
__global__ __launch_bounds__(256) void nchw_to_nhwc_kernel(
    const float* __restrict__ feat,   // (B, C, HF, WF)
    float*       __restrict__ featT)  // (B, HF, WF, C)
{
    const int bh = blockIdx.x;            // b*HF + h
    const int w0 = blockIdx.y << 6;       // 64-wide w tile
    const int b  = bh >> 7;               // / HF
    const int h  = bh & (HF - 1);
    const int tid = threadIdx.x;
#pragma unroll
    for (int k = 0; k < 16; ++k) {
        const int e = (k << 8) + tid;     // 0..4095
        const int c = e & 63;
        const int w = w0 + (e >> 6);
        const float v = feat[(((size_t)b * NC + c) * HF + h) * WF + w];
        // lanes contiguous in c -> 256B coalesced store
        featT[(((size_t)b * HF + h) * WF + w) * NC + c] = v;
    }
}

// ---- main: gather from NHWC, 16 channels per thread via 4x dwordx4/corner ----
__global__ __launch_bounds__(256) void RotatedROIPool_kernel(
    const float* __restrict__ featT,  // (B, HF, WF, C)
    const float* __restrict__ obb,    // (N, 5)
    const int*   __restrict__ bix,    // (N,)
    float*       __restrict__ out)    // (N, C, S, S)
{
    const int tid   = threadIdx.x;
    const int pid   = blockIdx.x;            // N * 16 patches
    const int n     = pid >> 4;
    const int patch = pid & 15;              // 4x4 patches of 16x16 samples
    const int pi    = (patch >> 2) << 4;
    const int pj    = (patch & 3)  << 4;

    // wave = 8x8 sub-patch: compact image footprint per gather instruction
    const int w    = tid >> 6;
    const int lane = tid & 63;
    const int i = pi + ((w >> 1) << 3) + (lane >> 3);
    const int j = pj + ((w & 1)  << 3) + (lane & 7);
    const int c0 = blockIdx.y * CT;          // channel tile (slow dim -> L2 phase sync)

    // --- per-ROI affine ---
    const float o0 = obb[n * 5 + 0];
    const float o1 = obb[n * 5 + 1];
    const float o2 = obb[n * 5 + 2];
    const float o3 = obb[n * 5 + 3];
    const float o4 = obb[n * 5 + 4];

    const float cx = o0 * FEAT_DOWN_INV;
    const float cy = o1 * FEAT_DOWN_INV;
    const float wsc = o2 * FEAT_DOWN_INV * EXPANDF;
    const float hsc = o3 * FEAT_DOWN_INV * EXPANDF;
    const float th = o4 * DEG2RADF;

    float sth, cth;
    sincosf(th, &sth, &cth);

    const float sx  = wsc * (1.0f / (float)S);
    const float sy  = hsc * (1.0f / (float)S);
    const float m00 = cth * sx;
    const float m01 = -sth * sy;
    const float m02 = cx;
    const float m10 = EXPANDF * sx;     // replicate reference exactly (diagonal quirk)
    const float m11 = cth * sy;
    const float m12 = cy;

    const float xg = (2.0f * (float)j + 1.0f) * (1.0f / (float)S) - 1.0f;
    const float yg = (2.0f * (float)i + 1.0f) * (1.0f / (float)S) - 1.0f;

    const float gx = m00 * xg + m01 * yg + m02;
    const float gy = m10 * xg + m11 * yg + m12;

    const float ix = ((gx + 1.0f) * (float)WF - 1.0f) * 0.5f;
    const float iy = ((gy + 1.0f) * (float)HF - 1.0f) * 0.5f;

    const float x0f = floorf(ix);
    const float y0f = floorf(iy);
    const float wx1 = ix - x0f;
    const float wy1 = iy - y0f;
    const float wx0 = 1.0f - wx1;
    const float wy0 = 1.0f - wy1;

    const int x0 = (int)x0f;
    const int y0 = (int)y0f;
    const int x1 = x0 + 1;
    const int y1 = y0 + 1;

    const float vx0 = (x0 >= 0 && x0 < WF) ? 1.0f : 0.0f;
    const float vx1 = (x1 >= 0 && x1 < WF) ? 1.0f : 0.0f;
    const float vy0 = (y0 >= 0 && y0 < HF) ? 1.0f : 0.0f;
    const float vy1 = (y1 >= 0 && y1 < HF) ? 1.0f : 0.0f;

    const float w00 = wy0 * wx0 * vy0 * vx0;
    const float w01 = wy0 * wx1 * vy0 * vx1;
    const float w10 = wy1 * wx0 * vy1 * vx0;
    const float w11 = wy1 * wx1 * vy1 * vx1;

    const int x0c = min(max(x0, 0), WF - 1);
    const int x1c = min(max(x1, 0), WF - 1);
    const int y0c = min(max(y0, 0), HF - 1);
    const int y1c = min(max(y1, 0), HF - 1);

    const int b = bix[n];
    const float* __restrict__ pt = featT + (size_t)b * HW * NC + c0;

    // corner base pointers: ((y*WF + x) * NC) floats; c0 multiple of 16 -> 64B aligned
    const float4* __restrict__ q00 = (const float4*)(pt + ((size_t)(y0c * WF + x0c) << 6));
    const float4* __restrict__ q01 = (const float4*)(pt + ((size_t)(y0c * WF + x1c) << 6));
    const float4* __restrict__ q10 = (const float4*)(pt + ((size_t)(y1c * WF + x0c) << 6));
    const float4* __restrict__ q11 = (const float4*)(pt + ((size_t)(y1c * WF + x1c) << 6));

    // issue all 16 loads (MLP); each corner's 4 dwordx4 hit one 64B line
    float4 a00[4], a01[4], a10[4], a11[4];
#pragma unroll
    for (int k = 0; k < 4; ++k) a00[k] = q00[k];
#pragma unroll
    for (int k = 0; k < 4; ++k) a01[k] = q01[k];
#pragma unroll
    for (int k = 0; k < 4; ++k) a10[k] = q10[k];
#pragma unroll
    for (int k = 0; k < 4; ++k) a11[k] = q11[k];

    float* __restrict__ op =
        out + (size_t)n * NC * SS + (size_t)c0 * SS + (size_t)i * S + (size_t)j;
#pragma unroll
    for (int k = 0; k < 4; ++k) {
        const float* f00 = (const float*)&a00[k];
        const float* f01 = (const float*)&a01[k];
        const float* f10 = (const float*)&a10[k];
        const float* f11 = (const float*)&a11[k];
#pragma unroll
        for (int c = 0; c < 4; ++c) {
            const float v = w00 * f00[c] + w01 * f01[c] + w10 * f10[c] + w11 * f11[c];
            *op = v;                          // normal store: L2 merges 32B halves
            op += SS;
        }
    }
}

// ---- fallback (ws too small): NCHW direct gather, CT=8 ----
__global__ __launch_bounds__(256) void RotatedROIPool_nchw_kernel(
    const float* __restrict__ feat, const float* __restrict__ obb,
    const int* __restrict__ bix, float* __restrict__ out)
{
    const int tid = threadIdx.x, pid = blockIdx.x;
    const int n = pid >> 4, patch = pid & 15;
    const int pi = (patch >> 2) << 4, pj = (patch & 3) << 4;
    const int w = tid >> 6, lane = tid & 63;
    const int i = pi + ((w >> 1) << 3) + (lane >> 3);
    const int j = pj + ((w & 1) << 3) + (lane & 7);
    const int c0 = blockIdx.y * 8;

    const float cx = obb[n*5+0]*FEAT_DOWN_INV, cy = obb[n*5+1]*FEAT_DOWN_INV;
    const float wsc = obb[n*5+2]*FEAT_DOWN_INV*EXPANDF, hsc = obb[n*5+3]*FEAT_DOWN_INV*EXPANDF;
    float sth, cth; sincosf(obb[n*5+4]*DEG2RADF, &sth, &cth);
    const float sx = wsc/(float)S, sy = hsc/(float)S;
    const float m00 = cth*sx, m01 = -sth*sy, m10 = EXPANDF*sx, m11 = cth*sy;
    const float xg = (2.f*j+1.f)/(float)S - 1.f, yg = (2.f*i+1.f)/(float)S - 1.f;
    const float gx = m00*xg + m01*yg + cx, gy = m10*xg + m11*yg + cy;
    const float ix = ((gx+1.f)*WF-1.f)*.5f, iy = ((gy+1.f)*HF-1.f)*.5f;
    const float x0f = floorf(ix), y0f = floorf(iy);
    const float wx1 = ix-x0f, wy1 = iy-y0f, wx0 = 1.f-wx1, wy0 = 1.f-wy1;
    const int x0 = (int)x0f, y0 = (int)y0f, x1 = x0+1, y1 = y0+1;
    const float vx0 = (x0>=0&&x0<WF)?1.f:0.f, vx1 = (x1>=0&&x1<WF)?1.f:0.f;
    const float vy0 = (y0>=0&&y0<HF)?1.f:0.f, vy1 = (y1>=0&&y1<HF)?1.f:0.f;
    const float w00 = wy0*wx0*vy0*vx0, w01 = wy0*wx1*vy0*vx1;
    const float w10 = wy1*wx0*vy1*vx0, w11 = wy1*wx1*vy1*vx1;
    const int x0c = min(max(x0,0),WF-1), x1c = min(max(x1,0),WF-1);
    const int y0c = min(max(y0,0),HF-1), y1c = min(max(y1,0),HF-1);
    const int o00 = y0c*WF+x0c, o01 = y0c*WF+x1c, o10 = y1c*WF+x0c, o11 = y1c*WF+x1c;
    const float* p = feat + (size_t)bix[n]*NC*HW + (size_t)c0*HW;
    float* op = out + (size_t)n*NC*SS + (size_t)c0*SS + (size_t)i*S + j;
#pragma unroll
    for (int g = 0; g < 2; ++g) {
        float v00[4], v01[4], v10[4], v11[4];
        const float* pc = p + (size_t)g*4*HW;
#pragma unroll
        for (int c = 0; c < 4; ++c) { v00[c]=pc[o00]; v01[c]=pc[o01]; v10[c]=pc[o10]; v11[c]=pc[o11]; pc += HW; }
        float* oc = op + (size_t)g*4*SS;
#pragma unroll
        for (int c = 0; c < 4; ++c) { *oc = w00*v00[c]+w01*v01[c]+w10*v10[c]+w11*v11[c]; oc += SS; }
    }
}

extern "C" void kernel_launch(void* const* d_in, const int* in_sizes, int n_in,
                              void* d_out, int out_size, void* d_ws, size_t ws_size,
                              hipStream_t stream) {
    const float* feat = (const float*)d_in[0];
    const float* obb  = (const float*)d_in[1];
    const int*   bx   = (const int*)d_in[2];
    float* out = (float*)d_out;

    const int N = in_sizes[1] / 5;                    // 256
    const int B = in_sizes[0] / (NC * HW);            // 2
    const size_t tbytes = (size_t)B * NC * HW * sizeof(float);  // 8 MB

    if (ws_size >= tbytes) {
        float* featT = (float*)d_ws;
        dim3 tg(B * HF, WF / 64, 1);
        nchw_to_nhwc_kernel<<<tg, 256, 0, stream>>>(feat, featT);
        dim3 grid(N * 16, NC / CT, 1);
        RotatedROIPool_kernel<<<grid, 256, 0, stream>>>(featT, obb, bx, out);
    } else {
        dim3 grid(N * 16, NC / 8, 1);
        RotatedROIPool_nchw_kernel<<<grid, 256, 0, stream>>>(feat, obb, bx, out);
    }
}

// Round 5
// 87.246 us; speedup vs baseline: 7.0872x; 2.0029x over previous
//
#include <hip/hip_runtime.h>
#include <math.h>

// Problem constants (match reference)
#define S 64
#define NC 64          // channels (C=64 -> one NHWC pixel = 256B contiguous)
#define HF 128
#define WF 128
#define HW (HF * WF)   // 16384
#define SS (S * S)     // 4096, channel stride in out
#define EXPANDF 1.25f
#define FEAT_DOWN_INV 0.125f
#define DEG2RADF 0.017453292519943295f

// ---- NCHW -> NHWC transpose, LDS-tiled (both sides coalesced) ----
__global__ __launch_bounds__(256) void nchw_to_nhwc_kernel(
    const float* __restrict__ feat,   // (B, C, HF, WF)
    float*       __restrict__ featT)  // (B, HF, WF, C)
{
    __shared__ float lds[64 * 65];
    const int bh  = blockIdx.x;           // b*HF + h
    const int b   = bh >> 7;
    const int h   = bh & (HF - 1);
    const int w0  = blockIdx.y << 6;      // 64-wide w tile
    const int tid = threadIdx.x;
    const int t4  = tid >> 6;             // 0..3
    const int t64 = tid & 63;

#pragma unroll
    for (int k = 0; k < 16; ++k) {        // read: lanes contiguous in w (256B)
        const int c = (k << 2) + t4;
        lds[t64 * 65 + c] = feat[(((size_t)b * NC + c) * HF + h) * WF + w0 + t64];
    }
    __syncthreads();
#pragma unroll
    for (int k = 0; k < 16; ++k) {        // write: lanes contiguous in c (256B)
        const int w = (k << 2) + t4;
        featT[(((size_t)b * HF + h) * WF + w0 + w) * NC + t64] = lds[w * 65 + t64];
    }
}

// ---- main: channel-in-lanes gather + LDS transpose to spatial-fast stores ----
// block = one (n, i) output row: 64 samples x 64 channels.
__global__ __launch_bounds__(256) void RotatedROIPool_kernel(
    const float* __restrict__ featT,  // (B, HF, WF, C)
    const float* __restrict__ obb,    // (N, 5)
    const int*   __restrict__ bix,    // (N,)
    float*       __restrict__ out,    // (N, C, S, S)
    int nwg_per_xcd)
{
    __shared__ float lds[64 * 65];    // [sample j][channel c], +1 pad

    // bijective XCD swizzle: consecutive rows of one ROI stay on one XCD (L2 reuse)
    const int bid = blockIdx.x;
    const int wg  = (bid & 7) * nwg_per_xcd + (bid >> 3);
    const int n   = wg >> 6;          // ROI
    const int i   = wg & 63;          // sample row

    const int tid  = threadIdx.x;
    const int wv   = tid >> 6;        // wave 0..3
    const int lane = tid & 63;
    const int s    = lane >> 4;       // sample-within-group 0..3
    const int c16  = lane & 15;       // channel group (4 floats each)

    // --- per-ROI affine ---
    const float o0 = obb[n * 5 + 0];
    const float o1 = obb[n * 5 + 1];
    const float o2 = obb[n * 5 + 2];
    const float o3 = obb[n * 5 + 3];
    const float o4 = obb[n * 5 + 4];

    const float cx  = o0 * FEAT_DOWN_INV;
    const float cy  = o1 * FEAT_DOWN_INV;
    const float wsc = o2 * FEAT_DOWN_INV * EXPANDF;
    const float hsc = o3 * FEAT_DOWN_INV * EXPANDF;
    const float th  = o4 * DEG2RADF;

    float sth, cth;
    sincosf(th, &sth, &cth);

    const float sx  = wsc * (1.0f / (float)S);
    const float sy  = hsc * (1.0f / (float)S);
    const float m00 = cth * sx;
    const float m01 = -sth * sy;
    const float m10 = EXPANDF * sx;   // replicate reference exactly (diagonal quirk)
    const float m11 = cth * sy;

    const float yg = (2.0f * (float)i + 1.0f) * (1.0f / (float)S) - 1.0f;
    const float hx = m01 * yg + cx;   // j-independent parts
    const float hy = m11 * yg + cy;

    const int b = bix[n];
    const float* __restrict__ pb = featT + (size_t)b * ((size_t)HW * NC);

    // --- phase 1: gather. wave covers j = wv*16 .. wv*16+15, 4 samples/iter ---
#pragma unroll
    for (int sg = 0; sg < 4; ++sg) {
        const int j = (wv << 4) + (sg << 2) + s;

        const float xg = (2.0f * (float)j + 1.0f) * (1.0f / (float)S) - 1.0f;
        const float gx = m00 * xg + hx;
        const float gy = m10 * xg + hy;

        const float ix = ((gx + 1.0f) * (float)WF - 1.0f) * 0.5f;
        const float iy = ((gy + 1.0f) * (float)HF - 1.0f) * 0.5f;

        const float x0f = floorf(ix);
        const float y0f = floorf(iy);
        const float wx1 = ix - x0f;
        const float wy1 = iy - y0f;
        const float wx0 = 1.0f - wx1;
        const float wy0 = 1.0f - wy1;

        const int x0 = (int)x0f;
        const int y0 = (int)y0f;
        const int x1 = x0 + 1;
        const int y1 = y0 + 1;

        const float vx0 = (x0 >= 0 && x0 < WF) ? 1.0f : 0.0f;
        const float vx1 = (x1 >= 0 && x1 < WF) ? 1.0f : 0.0f;
        const float vy0 = (y0 >= 0 && y0 < HF) ? 1.0f : 0.0f;
        const float vy1 = (y1 >= 0 && y1 < HF) ? 1.0f : 0.0f;

        const float w00 = wy0 * wx0 * vy0 * vx0;
        const float w01 = wy0 * wx1 * vy0 * vx1;
        const float w10 = wy1 * wx0 * vy1 * vx0;
        const float w11 = wy1 * wx1 * vy1 * vx1;

        const int x0c = min(max(x0, 0), WF - 1);
        const int x1c = min(max(x1, 0), WF - 1);
        const int y0c = min(max(y0, 0), HF - 1);
        const int y1c = min(max(y1, 0), HF - 1);

        // corner pixel base (floats); each pixel = 256B; lane adds c16*16B
        const float4* q00 = (const float4*)(pb + ((size_t)(y0c * WF + x0c) << 6)) + c16;
        const float4* q01 = (const float4*)(pb + ((size_t)(y0c * WF + x1c) << 6)) + c16;
        const float4* q10 = (const float4*)(pb + ((size_t)(y1c * WF + x0c) << 6)) + c16;
        const float4* q11 = (const float4*)(pb + ((size_t)(y1c * WF + x1c) << 6)) + c16;

        const float4 a00 = *q00;
        const float4 a01 = *q01;
        const float4 a10 = *q10;
        const float4 a11 = *q11;

        float4 v;
        v.x = w00 * a00.x + w01 * a01.x + w10 * a10.x + w11 * a11.x;
        v.y = w00 * a00.y + w01 * a01.y + w10 * a10.y + w11 * a11.y;
        v.z = w00 * a00.z + w01 * a01.z + w10 * a10.z + w11 * a11.z;
        v.w = w00 * a00.w + w01 * a01.w + w10 * a10.w + w11 * a11.w;

        // lds[j][4*c16 .. +3], stride 65: banks (j + 4*c16 + k)%32 -> 2-way (free)
        float* L = lds + j * 65 + (c16 << 2);
        L[0] = v.x; L[1] = v.y; L[2] = v.z; L[3] = v.w;
    }

    __syncthreads();

    // --- phase 2: transpose out. per iter: thread stores 4 j's of one channel ---
    float* __restrict__ ob = out + (size_t)n * NC * SS + (size_t)i * S;
    const int jg = tid & 15;          // j group (4 wide)
    const int cl = tid >> 4;          // 0..15
#pragma unroll
    for (int k = 0; k < 4; ++k) {
        const int c = (k << 4) + cl;
        float4 t;
        t.x = lds[(jg * 4 + 0) * 65 + c];
        t.y = lds[(jg * 4 + 1) * 65 + c];
        t.z = lds[(jg * 4 + 2) * 65 + c];
        t.w = lds[(jg * 4 + 3) * 65 + c];
        // wave = 4 channels x 16 lanes x 16B = 1KB fully coalesced
        *(float4*)(ob + (size_t)c * SS + (jg << 2)) = t;
    }
}

// ---- fallback (ws too small): NCHW direct gather, CT=8 ----
__global__ __launch_bounds__(256) void RotatedROIPool_nchw_kernel(
    const float* __restrict__ feat, const float* __restrict__ obb,
    const int* __restrict__ bix, float* __restrict__ out)
{
    const int tid = threadIdx.x, pid = blockIdx.x;
    const int n = pid >> 4, patch = pid & 15;
    const int pi = (patch >> 2) << 4, pj = (patch & 3) << 4;
    const int w = tid >> 6, lane = tid & 63;
    const int i = pi + ((w >> 1) << 3) + (lane >> 3);
    const int j = pj + ((w & 1) << 3) + (lane & 7);
    const int c0 = blockIdx.y * 8;

    const float cx = obb[n*5+0]*FEAT_DOWN_INV, cy = obb[n*5+1]*FEAT_DOWN_INV;
    const float wsc = obb[n*5+2]*FEAT_DOWN_INV*EXPANDF, hsc = obb[n*5+3]*FEAT_DOWN_INV*EXPANDF;
    float sth, cth; sincosf(obb[n*5+4]*DEG2RADF, &sth, &cth);
    const float sx = wsc/(float)S, sy = hsc/(float)S;
    const float m00 = cth*sx, m01 = -sth*sy, m10 = EXPANDF*sx, m11 = cth*sy;
    const float xg = (2.f*j+1.f)/(float)S - 1.f, yg = (2.f*i+1.f)/(float)S - 1.f;
    const float gx = m00*xg + m01*yg + cx, gy = m10*xg + m11*yg + cy;
    const float ix = ((gx+1.f)*WF-1.f)*.5f, iy = ((gy+1.f)*HF-1.f)*.5f;
    const float x0f = floorf(ix), y0f = floorf(iy);
    const float wx1 = ix-x0f, wy1 = iy-y0f, wx0 = 1.f-wx1, wy0 = 1.f-wy1;
    const int x0 = (int)x0f, y0 = (int)y0f, x1 = x0+1, y1 = y0+1;
    const float vx0 = (x0>=0&&x0<WF)?1.f:0.f, vx1 = (x1>=0&&x1<WF)?1.f:0.f;
    const float vy0 = (y0>=0&&y0<HF)?1.f:0.f, vy1 = (y1>=0&&y1<HF)?1.f:0.f;
    const float w00 = wy0*wx0*vy0*vx0, w01 = wy0*wx1*vy0*vx1;
    const float w10 = wy1*wx0*vy1*vx0, w11 = wy1*wx1*vy1*vx1;
    const int x0c = min(max(x0,0),WF-1), x1c = min(max(x1,0),WF-1);
    const int y0c = min(max(y0,0),HF-1), y1c = min(max(y1,0),HF-1);
    const int o00 = y0c*WF+x0c, o01 = y0c*WF+x1c, o10 = y1c*WF+x0c, o11 = y1c*WF+x1c;
    const float* p = feat + (size_t)bix[n]*NC*HW + (size_t)c0*HW;
    float* op = out + (size_t)n*NC*SS + (size_t)c0*SS + (size_t)i*S + j;
#pragma unroll
    for (int g = 0; g < 2; ++g) {
        float v00[4], v01[4], v10[4], v11[4];
        const float* pc = p + (size_t)g*4*HW;
#pragma unroll
        for (int c = 0; c < 4; ++c) { v00[c]=pc[o00]; v01[c]=pc[o01]; v10[c]=pc[o10]; v11[c]=pc[o11]; pc += HW; }
        float* oc = op + (size_t)g*4*SS;
#pragma unroll
        for (int c = 0; c < 4; ++c) { *oc = w00*v00[c]+w01*v01[c]+w10*v10[c]+w11*v11[c]; oc += SS; }
    }
}

extern "C" void kernel_launch(void* const* d_in, const int* in_sizes, int n_in,
                              void* d_out, int out_size, void* d_ws, size_t ws_size,
                              hipStream_t stream) {
    const float* feat = (const float*)d_in[0];
    const float* obb  = (const float*)d_in[1];
    const int*   bx   = (const int*)d_in[2];
    float* out = (float*)d_out;

    const int N = in_sizes[1] / 5;                    // 256
    const int B = in_sizes[0] / (NC * HW);            // 2
    const size_t tbytes = (size_t)B * NC * HW * sizeof(float);  // 8 MB

    if (ws_size >= tbytes) {
        float* featT = (float*)d_ws;
        dim3 tg(B * HF, WF / 64, 1);
        nchw_to_nhwc_kernel<<<tg, 256, 0, stream>>>(feat, featT);

        const int nwg = N * S;                        // 16384, divisible by 8
        RotatedROIPool_kernel<<<nwg, 256, 0, stream>>>(featT, obb, bx, out, nwg / 8);
    } else {
        dim3 grid(N * 16, NC / 8, 1);
        RotatedROIPool_nchw_kernel<<<grid, 256, 0, stream>>>(feat, obb, bx, out);
    }
}

// Round 6
// 66.630 us; speedup vs baseline: 9.2801x; 1.3094x over previous
//
#include <hip/hip_runtime.h>
#include <math.h>

// Problem constants (match reference)
#define S 64
#define NC 64          // channels (C=64 -> one NHWC bf16 pixel = 128B contiguous)
#define HF 128
#define WF 128
#define HW (HF * WF)   // 16384
#define SS (S * S)     // 4096, channel stride in out
#define EXPANDF 1.25f
#define FEAT_DOWN_INV 0.125f
#define DEG2RADF 0.017453292519943295f

__device__ __forceinline__ unsigned int f32_to_bf16_rne(float v) {
    unsigned int u = __float_as_uint(v);
    return (u + 0x7FFFu + ((u >> 16) & 1u)) >> 16;   // finite data: no NaN concern
}
__device__ __forceinline__ float bf16_bits_to_f32(unsigned int h) {
    return __uint_as_float(h << 16);
}

// ---- NCHW f32 -> NHWC bf16 transpose, LDS-tiled (both sides coalesced) ----
__global__ __launch_bounds__(256) void nchw_to_nhwc_bf16_kernel(
    const float*    __restrict__ feat,    // (B, C, HF, WF) f32
    unsigned short* __restrict__ featT)   // (B, HF, WF, C) bf16
{
    __shared__ float lds[64 * 65];
    const int bh  = blockIdx.x;           // b*HF + h
    const int b   = bh >> 7;
    const int h   = bh & (HF - 1);
    const int w0  = blockIdx.y << 6;      // 64-wide w tile
    const int tid = threadIdx.x;
    const int t4  = tid >> 6;             // 0..3
    const int t64 = tid & 63;

#pragma unroll
    for (int k = 0; k < 16; ++k) {        // read: lanes contiguous in w (256B)
        const int c = (k << 2) + t4;
        lds[t64 * 65 + c] = feat[(((size_t)b * NC + c) * HF + h) * WF + w0 + t64];
    }
    __syncthreads();
#pragma unroll
    for (int k = 0; k < 16; ++k) {        // write: lanes contiguous in c (128B)
        const int w = (k << 2) + t4;
        featT[(((size_t)b * HF + h) * WF + w0 + w) * NC + t64] =
            (unsigned short)f32_to_bf16_rne(lds[w * 65 + t64]);
    }
}

// ---- main: channel-in-lanes bf16 gather + LDS transpose to spatial-fast stores ----
// block = one (n, i) output row: 64 samples x 64 channels.
__global__ __launch_bounds__(256) void RotatedROIPool_kernel(
    const unsigned short* __restrict__ featT,  // (B, HF, WF, C) bf16
    const float*          __restrict__ obb,    // (N, 5)
    const int*            __restrict__ bix,    // (N,)
    float*                __restrict__ out,    // (N, C, S, S)
    int nwg_per_xcd)
{
    __shared__ float lds[64 * 65];    // [sample j][channel c], +1 pad (R4-proven 0-conflict)

    // bijective XCD swizzle: consecutive rows of one ROI stay on one XCD (L2 reuse)
    const int bid = blockIdx.x;
    const int wg  = (bid & 7) * nwg_per_xcd + (bid >> 3);
    const int n   = wg >> 6;          // ROI
    const int i   = wg & 63;          // sample row

    const int tid  = threadIdx.x;
    const int wv   = tid >> 6;        // wave 0..3
    const int lane = tid & 63;
    const int s    = lane >> 3;       // sample-within-group 0..7
    const int c8   = lane & 7;        // channel group (8 bf16 = 16B each)

    // --- per-ROI affine ---
    const float o0 = obb[n * 5 + 0];
    const float o1 = obb[n * 5 + 1];
    const float o2 = obb[n * 5 + 2];
    const float o3 = obb[n * 5 + 3];
    const float o4 = obb[n * 5 + 4];

    const float cx  = o0 * FEAT_DOWN_INV;
    const float cy  = o1 * FEAT_DOWN_INV;
    const float wsc = o2 * FEAT_DOWN_INV * EXPANDF;
    const float hsc = o3 * FEAT_DOWN_INV * EXPANDF;
    const float th  = o4 * DEG2RADF;

    float sth, cth;
    sincosf(th, &sth, &cth);

    const float sx  = wsc * (1.0f / (float)S);
    const float sy  = hsc * (1.0f / (float)S);
    const float m00 = cth * sx;
    const float m01 = -sth * sy;
    const float m10 = EXPANDF * sx;   // replicate reference exactly (diagonal quirk)
    const float m11 = cth * sy;

    const float yg = (2.0f * (float)i + 1.0f) * (1.0f / (float)S) - 1.0f;
    const float hx = m01 * yg + cx;   // j-independent parts
    const float hy = m11 * yg + cy;

    const int b = bix[n];
    const unsigned char* __restrict__ pb =
        (const unsigned char*)featT + (size_t)b * ((size_t)HW * NC * 2);

    // --- phase 1: gather. wave covers j = wv*16 .. wv*16+15, 8 samples/iter ---
#pragma unroll
    for (int sg = 0; sg < 2; ++sg) {
        const int j = (wv << 4) + (sg << 3) + s;

        const float xg = (2.0f * (float)j + 1.0f) * (1.0f / (float)S) - 1.0f;
        const float gx = m00 * xg + hx;
        const float gy = m10 * xg + hy;

        const float ix = ((gx + 1.0f) * (float)WF - 1.0f) * 0.5f;
        const float iy = ((gy + 1.0f) * (float)HF - 1.0f) * 0.5f;

        const float x0f = floorf(ix);
        const float y0f = floorf(iy);
        const float wx1 = ix - x0f;
        const float wy1 = iy - y0f;
        const float wx0 = 1.0f - wx1;
        const float wy0 = 1.0f - wy1;

        const int x0 = (int)x0f;
        const int y0 = (int)y0f;
        const int x1 = x0 + 1;
        const int y1 = y0 + 1;

        const float vx0 = (x0 >= 0 && x0 < WF) ? 1.0f : 0.0f;
        const float vx1 = (x1 >= 0 && x1 < WF) ? 1.0f : 0.0f;
        const float vy0 = (y0 >= 0 && y0 < HF) ? 1.0f : 0.0f;
        const float vy1 = (y1 >= 0 && y1 < HF) ? 1.0f : 0.0f;

        const float w00 = wy0 * wx0 * vy0 * vx0;
        const float w01 = wy0 * wx1 * vy0 * vx1;
        const float w10 = wy1 * wx0 * vy1 * vx0;
        const float w11 = wy1 * wx1 * vy1 * vx1;

        const int x0c = min(max(x0, 0), WF - 1);
        const int x1c = min(max(x1, 0), WF - 1);
        const int y0c = min(max(y0, 0), HF - 1);
        const int y1c = min(max(y1, 0), HF - 1);

        // bf16 pixel = 128B; lane adds c8*16B -> one instr covers 8 pixels, all lines full
        const uint4 a00 = *((const uint4*)(pb + ((size_t)(y0c * WF + x0c) << 7)) + c8);
        const uint4 a01 = *((const uint4*)(pb + ((size_t)(y0c * WF + x1c) << 7)) + c8);
        const uint4 a10 = *((const uint4*)(pb + ((size_t)(y1c * WF + x0c) << 7)) + c8);
        const uint4 a11 = *((const uint4*)(pb + ((size_t)(y1c * WF + x1c) << 7)) + c8);

        const unsigned int* u00 = (const unsigned int*)&a00;
        const unsigned int* u01 = (const unsigned int*)&a01;
        const unsigned int* u10 = (const unsigned int*)&a10;
        const unsigned int* u11 = (const unsigned int*)&a11;

        // lds[j][8*c8 + m], stride 65: banks (j + 8*c8 + m)%32 -> exact 2-way (free)
        float* L = lds + j * 65 + (c8 << 3);
#pragma unroll
        for (int m = 0; m < 4; ++m) {
            const float f00l = bf16_bits_to_f32(u00[m] & 0xFFFFu);
            const float f01l = bf16_bits_to_f32(u01[m] & 0xFFFFu);
            const float f10l = bf16_bits_to_f32(u10[m] & 0xFFFFu);
            const float f11l = bf16_bits_to_f32(u11[m] & 0xFFFFu);
            const float f00h = bf16_bits_to_f32(u00[m] >> 16);
            const float f01h = bf16_bits_to_f32(u01[m] >> 16);
            const float f10h = bf16_bits_to_f32(u10[m] >> 16);
            const float f11h = bf16_bits_to_f32(u11[m] >> 16);
            L[2 * m + 0] = w00 * f00l + w01 * f01l + w10 * f10l + w11 * f11l;
            L[2 * m + 1] = w00 * f00h + w01 * f01h + w10 * f10h + w11 * f11h;
        }
    }

    __syncthreads();

    // --- phase 2: transpose out (identical to R4; proven coalesced, 0 conflicts) ---
    float* __restrict__ ob = out + (size_t)n * NC * SS + (size_t)i * S;
    const int jg = tid & 15;          // j group (4 wide)
    const int cl = tid >> 4;          // 0..15
#pragma unroll
    for (int k = 0; k < 4; ++k) {
        const int c = (k << 4) + cl;
        float4 t;
        t.x = lds[(jg * 4 + 0) * 65 + c];
        t.y = lds[(jg * 4 + 1) * 65 + c];
        t.z = lds[(jg * 4 + 2) * 65 + c];
        t.w = lds[(jg * 4 + 3) * 65 + c];
        *(float4*)(ob + (size_t)c * SS + (jg << 2)) = t;
    }
}

// ---- fallback (ws too small): NCHW f32 direct gather, CT=8 ----
__global__ __launch_bounds__(256) void RotatedROIPool_nchw_kernel(
    const float* __restrict__ feat, const float* __restrict__ obb,
    const int* __restrict__ bix, float* __restrict__ out)
{
    const int tid = threadIdx.x, pid = blockIdx.x;
    const int n = pid >> 4, patch = pid & 15;
    const int pi = (patch >> 2) << 4, pj = (patch & 3) << 4;
    const int w = tid >> 6, lane = tid & 63;
    const int i = pi + ((w >> 1) << 3) + (lane >> 3);
    const int j = pj + ((w & 1) << 3) + (lane & 7);
    const int c0 = blockIdx.y * 8;

    const float cx = obb[n*5+0]*FEAT_DOWN_INV, cy = obb[n*5+1]*FEAT_DOWN_INV;
    const float wsc = obb[n*5+2]*FEAT_DOWN_INV*EXPANDF, hsc = obb[n*5+3]*FEAT_DOWN_INV*EXPANDF;
    float sth, cth; sincosf(obb[n*5+4]*DEG2RADF, &sth, &cth);
    const float sx = wsc/(float)S, sy = hsc/(float)S;
    const float m00 = cth*sx, m01 = -sth*sy, m10 = EXPANDF*sx, m11 = cth*sy;
    const float xg = (2.f*j+1.f)/(float)S - 1.f, yg = (2.f*i+1.f)/(float)S - 1.f;
    const float gx = m00*xg + m01*yg + cx, gy = m10*xg + m11*yg + cy;
    const float ix = ((gx+1.f)*WF-1.f)*.5f, iy = ((gy+1.f)*HF-1.f)*.5f;
    const float x0f = floorf(ix), y0f = floorf(iy);
    const float wx1 = ix-x0f, wy1 = iy-y0f, wx0 = 1.f-wx1, wy0 = 1.f-wy1;
    const int x0 = (int)x0f, y0 = (int)y0f, x1 = x0+1, y1 = y0+1;
    const float vx0 = (x0>=0&&x0<WF)?1.f:0.f, vx1 = (x1>=0&&x1<WF)?1.f:0.f;
    const float vy0 = (y0>=0&&y0<HF)?1.f:0.f, vy1 = (y1>=0&&y1<HF)?1.f:0.f;
    const float w00 = wy0*wx0*vy0*vx0, w01 = wy0*wx1*vy0*vx1;
    const float w10 = wy1*wx0*vy1*vx0, w11 = wy1*wx1*vy1*vx1;
    const int x0c = min(max(x0,0),WF-1), x1c = min(max(x1,0),WF-1);
    const int y0c = min(max(y0,0),HF-1), y1c = min(max(y1,0),HF-1);
    const int o00 = y0c*WF+x0c, o01 = y0c*WF+x1c, o10 = y1c*WF+x0c, o11 = y1c*WF+x1c;
    const float* p = feat + (size_t)bix[n]*NC*HW + (size_t)c0*HW;
    float* op = out + (size_t)n*NC*SS + (size_t)c0*SS + (size_t)i*S + j;
#pragma unroll
    for (int g = 0; g < 2; ++g) {
        float v00[4], v01[4], v10[4], v11[4];
        const float* pc = p + (size_t)g*4*HW;
#pragma unroll
        for (int c = 0; c < 4; ++c) { v00[c]=pc[o00]; v01[c]=pc[o01]; v10[c]=pc[o10]; v11[c]=pc[o11]; pc += HW; }
        float* oc = op + (size_t)g*4*SS;
#pragma unroll
        for (int c = 0; c < 4; ++c) { *oc = w00*v00[c]+w01*v01[c]+w10*v10[c]+w11*v11[c]; oc += SS; }
    }
}

extern "C" void kernel_launch(void* const* d_in, const int* in_sizes, int n_in,
                              void* d_out, int out_size, void* d_ws, size_t ws_size,
                              hipStream_t stream) {
    const float* feat = (const float*)d_in[0];
    const float* obb  = (const float*)d_in[1];
    const int*   bx   = (const int*)d_in[2];
    float* out = (float*)d_out;

    const int N = in_sizes[1] / 5;                    // 256
    const int B = in_sizes[0] / (NC * HW);            // 2
    const size_t tbytes = (size_t)B * NC * HW * sizeof(unsigned short);  // 4 MB

    if (ws_size >= tbytes) {
        unsigned short* featT = (unsigned short*)d_ws;
        dim3 tg(B * HF, WF / 64, 1);
        nchw_to_nhwc_bf16_kernel<<<tg, 256, 0, stream>>>(feat, featT);

        const int nwg = N * S;                        // 16384, divisible by 8
        RotatedROIPool_kernel<<<nwg, 256, 0, stream>>>(featT, obb, bx, out, nwg / 8);
    } else {
        dim3 grid(N * 16, NC / 8, 1);
        RotatedROIPool_nchw_kernel<<<grid, 256, 0, stream>>>(feat, obb, bx, out);
    }
}